// Round 4
// baseline (128.708 us; speedup 1.0000x reference)
//
#include <hip/hip_runtime.h>
#include <math.h>

#define N 256
#define NN (N * N)      // 65536
#define NNN (N * N * N) // 16777216

__device__ inline float4 f4max(float4 a, float4 b) {
  return make_float4(fmaxf(a.x, b.x), fmaxf(a.y, b.y), fmaxf(a.z, b.z), fmaxf(a.w, b.w));
}
__device__ inline float4 f4add(float4 a, float4 b) {
  return make_float4(a.x + b.x, a.y + b.y, a.z + b.z, a.w + b.w);
}
__device__ inline float4 f4scale(float4 a, float f) {
  return make_float4(a.x * f, a.y * f, a.z * f, a.w * f);
}

// ===== fused reduction kernel (split for occupancy) =====
// blocks [0, 2BN):    cw blocks: blk>>1 = (b,h), blk&1 = c-half
//   c-reduction (its 128 c's)  -> zA{half}[b][h][w]  (partial, merged in conv)
//   w-reduction (full w)       -> zC[b][h][c] for its 128 c's (complete)
// blocks [2BN, 4BN):  h blocks: (blk-2BN)>>1 = (b,c), &1 = h-half
//   h-reduction (its 128 h's)  -> zB{half}[b][c][w]  (partial, merged in conv)
__global__ __launch_bounds__(256) void reduce_all_kernel(
    const float* __restrict__ x,
    float* __restrict__ zA0max, float* __restrict__ zA0mean,
    float* __restrict__ zA1max, float* __restrict__ zA1mean,
    float* __restrict__ zB0max, float* __restrict__ zB0mean,
    float* __restrict__ zB1max, float* __restrict__ zB1mean,
    float* __restrict__ zCmax, float* __restrict__ zCmean,
    int BN) {
  __shared__ float pm[128][9];  // 8 w-partials (max) per local c-row, pad 9
  __shared__ float ps[128][9];  // 8 w-partials (sum)
  __shared__ float gpa[4][N];   // per-wave elementwise partial (max)
  __shared__ float gpb[4][N];   // per-wave elementwise partial (sum)

  const int lane = threadIdx.x & 63;
  const int g = threadIdx.x >> 6;  // wave 0..3
  const int blk = blockIdx.x;

  if (blk < 2 * BN) {
    // ---------- c-reduction (half) + w-reduction ----------
    const int half = blk & 1;
    const int bh = blk >> 1;
    const int b = bh >> 8, h = bh & 255;
    const int c0 = half * 128 + g * 32;  // this wave's c range: [c0, c0+32)
    const float* base = x + (size_t)b * NNN + (size_t)h * N + (lane << 2);
    float4 accm = make_float4(-INFINITY, -INFINITY, -INFINITY, -INFINITY);
    float4 accs = make_float4(0.f, 0.f, 0.f, 0.f);
#pragma unroll 4
    for (int cc = 0; cc < 32; ++cc) {
      float4 v = *(const float4*)(base + (size_t)(c0 + cc) * NN);
      accm = f4max(accm, v);
      accs = f4add(accs, v);
      float m = fmaxf(fmaxf(v.x, v.y), fmaxf(v.z, v.w));
      float s = v.x + v.y + v.z + v.w;
      m = fmaxf(m, __shfl_xor(m, 1));
      s += __shfl_xor(s, 1);
      m = fmaxf(m, __shfl_xor(m, 2));
      s += __shfl_xor(s, 2);
      m = fmaxf(m, __shfl_xor(m, 4));
      s += __shfl_xor(s, 4);
      if ((lane & 7) == 0) {
        const int cl = g * 32 + cc;  // local c 0..127
        pm[cl][lane >> 3] = m;
        ps[cl][lane >> 3] = s;
      }
    }
    const int w4 = lane << 2;
    *(float4*)&gpa[g][w4] = accm;
    *(float4*)&gpb[g][w4] = accs;
    __syncthreads();
    // finalize partial zA (this c-half): one thread per w; mean stored as sum/256
    {
      const int w = threadIdx.x;
      float m = fmaxf(fmaxf(gpa[0][w], gpa[1][w]), fmaxf(gpa[2][w], gpa[3][w]));
      float s = (gpb[0][w] + gpb[1][w] + gpb[2][w] + gpb[3][w]) * (1.f / 256.f);
      float* zm = half ? zA1max : zA0max;
      float* zs = half ? zA1mean : zA0mean;
      zm[(size_t)bh * N + w] = m;
      zs[(size_t)bh * N + w] = s;
    }
    // finalize zC for this block's 128 c's (complete over w)
    if (threadIdx.x < 128) {
      const int cl = threadIdx.x;
      float m = pm[cl][0], s = ps[cl][0];
#pragma unroll
      for (int i = 1; i < 8; ++i) {
        m = fmaxf(m, pm[cl][i]);
        s += ps[cl][i];
      }
      zCmax[(size_t)bh * N + half * 128 + cl] = m;
      zCmean[(size_t)bh * N + half * 128 + cl] = s * (1.f / 256.f);
    }
  } else {
    // ---------- h-reduction (half) ----------
    const int blk2 = blk - 2 * BN;
    const int half = blk2 & 1;
    const int bc = blk2 >> 1;            // b*N + c
    const int b = bc >> 8, c = bc & 255;
    const int w4 = lane << 2;
    const int h0 = half * 128 + g * 32;  // this wave's h range
    const float* p = x + (size_t)b * NNN + (size_t)c * NN + (size_t)h0 * N + w4;
    float4 m = make_float4(-INFINITY, -INFINITY, -INFINITY, -INFINITY);
    float4 s = make_float4(0.f, 0.f, 0.f, 0.f);
#pragma unroll 8
    for (int hh = 0; hh < 32; ++hh) {
      float4 v = *(const float4*)(p + (size_t)hh * N);
      m = f4max(m, v);
      s = f4add(s, v);
    }
    *(float4*)&gpa[g][w4] = m;
    *(float4*)&gpb[g][w4] = s;
    __syncthreads();
    if (g == 0) {
      float4 m0 = *(float4*)&gpa[0][w4];
      float4 m1 = *(float4*)&gpa[1][w4];
      float4 m2 = *(float4*)&gpa[2][w4];
      float4 m3 = *(float4*)&gpa[3][w4];
      float4 s0 = *(float4*)&gpb[0][w4];
      float4 s1 = *(float4*)&gpb[1][w4];
      float4 s2 = *(float4*)&gpb[2][w4];
      float4 s3 = *(float4*)&gpb[3][w4];
      float4 mm = f4max(f4max(m0, m1), f4max(m2, m3));
      float4 ss = f4scale(f4add(f4add(s0, s1), f4add(s2, s3)), 1.f / 256.f);
      float* zm = half ? zB1max : zB0max;
      float* zs = half ? zB1mean : zB0mean;
      *(float4*)(zm + (size_t)bc * N + w4) = mm;
      *(float4*)(zs + (size_t)bc * N + w4) = ss;
    }
  }
}

// -------- fused 7x7 conv (2ch->1) + BN + sigmoid for ALL THREE gates --------
// branches 0/1 merge two half-partials (max via fmax, mean via add) on the fly
__global__ __launch_bounds__(256) void conv_gate3_kernel(
    const float* __restrict__ zA0max, const float* __restrict__ zA0mean,
    const float* __restrict__ zA1max, const float* __restrict__ zA1mean,
    const float* __restrict__ zB0max, const float* __restrict__ zB0mean,
    const float* __restrict__ zB1max, const float* __restrict__ zB1mean,
    const float* __restrict__ zCmax, const float* __restrict__ zCmean,
    const float* __restrict__ w_hw, const float* __restrict__ g_hw,
    const float* __restrict__ b_hw, const float* __restrict__ m_hw,
    const float* __restrict__ v_hw,
    const float* __restrict__ w_hc, const float* __restrict__ g_hc,
    const float* __restrict__ b_hc, const float* __restrict__ m_hc,
    const float* __restrict__ v_hc,
    const float* __restrict__ w_wc, const float* __restrict__ g_wc,
    const float* __restrict__ b_wc, const float* __restrict__ m_wc,
    const float* __restrict__ v_wc,
    float* __restrict__ Ghw, float* __restrict__ Ghc, float* __restrict__ Gwc,
    int BN) {
  const int branch = blockIdx.x / BN;
  const int bp = blockIdx.x - branch * BN;  // b*N + p
  const int b = bp >> 8, p = bp & 255;
  const float *zm0, *zm1, *za0, *za1;
  const float *wt, *gg, *bb, *mm, *vv;
  float* gate;
  bool dual;
  if (branch == 0) {
    zm0 = zA0max; zm1 = zA1max; za0 = zA0mean; za1 = zA1mean; dual = true;
    wt = w_hw; gg = g_hw; bb = b_hw; mm = m_hw; vv = v_hw; gate = Ghw;
  } else if (branch == 1) {
    zm0 = zB0max; zm1 = zB1max; za0 = zB0mean; za1 = zB1mean; dual = true;
    wt = w_hc; gg = g_hc; bb = b_hc; mm = m_hc; vv = v_hc; gate = Ghc;
  } else {
    zm0 = zCmax; zm1 = zCmax; za0 = zCmean; za1 = zCmean; dual = false;
    wt = w_wc; gg = g_wc; bb = b_wc; mm = m_wc; vv = v_wc; gate = Gwc;
  }
  const int q = threadIdx.x;
  const size_t boff = (size_t)b * NN;
  zm0 += boff; zm1 += boff; za0 += boff; za1 += boff;
  float y = 0.f;
#pragma unroll
  for (int dh = 0; dh < 7; ++dh) {
    const int pp = p + dh - 3;
    if ((unsigned)pp < N) {
#pragma unroll
      for (int dw = 0; dw < 7; ++dw) {
        const int qq = q + dw - 3;
        if ((unsigned)qq < N) {
          const int idx = pp * N + qq;
          const float zm = dual ? fmaxf(zm0[idx], zm1[idx]) : zm0[idx];
          const float za = dual ? (za0[idx] + za1[idx]) : za0[idx];
          y += zm * wt[dh * 7 + dw] + za * wt[49 + dh * 7 + dw];
        }
      }
    }
  }
  const float scale = gg[0] * rsqrtf(vv[0] + 1e-5f);
  const float yb = (y - mm[0]) * scale + bb[0];
  gate[(size_t)bp * N + q] = 1.f / (1.f + __expf(-yb));
}

// -------- final combine --------
// out[b,i,j,k] = ( x[b,i,j,k]*(Ghw[b,j,k]+Ghc[b,i,k]) + x[b,k,i,j]*Gwc[b,i,k] ) / 3
__global__ __launch_bounds__(256) void combine_kernel(
    const float* __restrict__ x, const float* __restrict__ Ghw,
    const float* __restrict__ Ghc, const float* __restrict__ Gwc,
    float* __restrict__ out) {
  __shared__ float t[32][33]; // t[kk][jj] = x[b, k0+kk, i, j0+jj]
  const int blk = blockIdx.x;
  const int kt = blk & 7, jt = (blk >> 3) & 7, i = (blk >> 6) & 255, b = blk >> 14;
  const int k0 = kt << 5, j0 = jt << 5;
  const int rowi = threadIdx.x >> 3;        // 0..31
  const int col4 = (threadIdx.x & 7) << 2;  // 0,4,...,28
  {
    float4 v = *(const float4*)(x + ((size_t)b << 24) + ((size_t)(k0 + rowi) << 16) +
                                ((size_t)i << 8) + j0 + col4);
    t[rowi][col4 + 0] = v.x;
    t[rowi][col4 + 1] = v.y;
    t[rowi][col4 + 2] = v.z;
    t[rowi][col4 + 3] = v.w;
  }
  __syncthreads();
  const int jj = rowi;        // output row within tile
  const int k = k0 + col4;    // output col quad
  const size_t gik = (((size_t)(b << 8) + i) << 8) + k; // (b*N+i)*N + k
  const float4 ghc = *(const float4*)(Ghc + gik);
  const float4 gwc = *(const float4*)(Gwc + gik);
  const size_t base = ((size_t)b << 24) + ((size_t)i << 16) + ((size_t)(j0 + jj) << 8) + k;
  const float4 xv = *(const float4*)(x + base);
  const float4 ghw = *(const float4*)(Ghw + ((size_t)b << 16) + ((size_t)(j0 + jj) << 8) + k);
  const float third = 1.f / 3.f;
  float4 r;
  r.x = (xv.x * (ghw.x + ghc.x) + t[col4 + 0][jj] * gwc.x) * third;
  r.y = (xv.y * (ghw.y + ghc.y) + t[col4 + 1][jj] * gwc.y) * third;
  r.z = (xv.z * (ghw.z + ghc.z) + t[col4 + 2][jj] * gwc.z) * third;
  r.w = (xv.w * (ghw.w + ghc.w) + t[col4 + 3][jj] * gwc.w) * third;
  *(float4*)(out + base) = r;
}

extern "C" void kernel_launch(void* const* d_in, const int* in_sizes, int n_in,
                              void* d_out, int out_size, void* d_ws, size_t ws_size,
                              hipStream_t stream) {
  const float* x    = (const float*)d_in[0];
  const float* w_hw = (const float*)d_in[1];
  const float* g_hw = (const float*)d_in[2];
  const float* b_hw = (const float*)d_in[3];
  const float* m_hw = (const float*)d_in[4];
  const float* v_hw = (const float*)d_in[5];
  const float* w_hc = (const float*)d_in[6];
  const float* g_hc = (const float*)d_in[7];
  const float* b_hc = (const float*)d_in[8];
  const float* m_hc = (const float*)d_in[9];
  const float* v_hc = (const float*)d_in[10];
  const float* w_wc = (const float*)d_in[11];
  const float* g_wc = (const float*)d_in[12];
  const float* b_wc = (const float*)d_in[13];
  const float* m_wc = (const float*)d_in[14];
  const float* v_wc = (const float*)d_in[15];

  const int B = in_sizes[0] / NNN; // 2
  const int BN = B * N;
  const size_t plane = (size_t)B * NN;
  float* ws = (float*)d_ws;
  float* zA0max  = ws + 0 * plane;
  float* zA0mean = ws + 1 * plane;
  float* zA1max  = ws + 2 * plane;
  float* zA1mean = ws + 3 * plane;
  float* zB0max  = ws + 4 * plane;
  float* zB0mean = ws + 5 * plane;
  float* zB1max  = ws + 6 * plane;
  float* zB1mean = ws + 7 * plane;
  float* zCmax   = ws + 8 * plane;
  float* zCmean  = ws + 9 * plane;
  float* GhwP    = ws + 10 * plane;
  float* GhcP    = ws + 11 * plane;
  float* GwcP    = ws + 12 * plane;

  reduce_all_kernel<<<4 * BN, 256, 0, stream>>>(
      x, zA0max, zA0mean, zA1max, zA1mean,
      zB0max, zB0mean, zB1max, zB1mean, zCmax, zCmean, BN);

  conv_gate3_kernel<<<3 * BN, 256, 0, stream>>>(
      zA0max, zA0mean, zA1max, zA1mean,
      zB0max, zB0mean, zB1max, zB1mean, zCmax, zCmean,
      w_hw, g_hw, b_hw, m_hw, v_hw,
      w_hc, g_hc, b_hc, m_hc, v_hc,
      w_wc, g_wc, b_wc, m_wc, v_wc,
      GhwP, GhcP, GwcP, BN);

  combine_kernel<<<B * N * 64, 256, 0, stream>>>(x, GhwP, GhcP, GwcP, (float*)d_out);
}